// Round 4
// baseline (434.351 us; speedup 1.0000x reference)
//
#include <hip/hip_runtime.h>
#include <stdint.h>

#define N_PTS 240000
#define NV    11059200      // 2*480*360*32 voxels
#define NWORDS 172800       // NV/64 bitmap words
#define NB_PT 938           // ceil(N_PTS/256)
#define NB_WORD 675         // NWORDS/256 (exact)
#define NBLK_MLP 3750       // N_PTS/64

typedef __bf16 bf16x8 __attribute__((ext_vector_type(8)));
typedef short  short8 __attribute__((ext_vector_type(8)));
typedef float  f32x4  __attribute__((ext_vector_type(4)));

__device__ __forceinline__ unsigned short f2bf(float f) {
  unsigned u = __builtin_bit_cast(unsigned, f);
  return (unsigned short)((u + 0x7FFFu + ((u >> 16) & 1u)) >> 16);   // RNE
}
__device__ __forceinline__ float bf2f(unsigned short h) {
  unsigned u = ((unsigned)h) << 16;
  return __builtin_bit_cast(float, u);
}

// ---------------- weight prep: fold BN into linear weights, transpose to [C][K] bf16 ----
__global__ void prep_kernel(
    const float* __restrict__ bng0, const float* __restrict__ bnb0, const float* __restrict__ bnm0, const float* __restrict__ bnv0,
    const float* __restrict__ bng1, const float* __restrict__ bnb1, const float* __restrict__ bnm1, const float* __restrict__ bnv1,
    const float* __restrict__ bng2, const float* __restrict__ bnb2, const float* __restrict__ bnm2, const float* __restrict__ bnv2,
    const float* __restrict__ bng3, const float* __restrict__ bnb3, const float* __restrict__ bnm3, const float* __restrict__ bnv3,
    const float* __restrict__ w1, const float* __restrict__ b1,
    const float* __restrict__ w2, const float* __restrict__ b2,
    const float* __restrict__ w3, const float* __restrict__ b3,
    const float* __restrict__ w4, const float* __restrict__ wc,
    float* __restrict__ s0, float* __restrict__ t0, float* __restrict__ w1e, float* __restrict__ be1,
    float* __restrict__ be2, float* __restrict__ be3,
    unsigned short* __restrict__ w2t, unsigned short* __restrict__ w3t, unsigned short* __restrict__ w4t,
    unsigned short* __restrict__ wct)
{
  const int id = blockIdx.x * 256 + threadIdx.x;   // grid covers 65536 exactly
  { int c = id >> 8, k = id & 255; w4t[c * 256 + k] = f2bf(w4[k * 256 + c]); }
  if (id < 32768) { int c = id >> 7, k = id & 127;
    float s = bng3[c] * rsqrtf(bnv3[c] + 1e-5f);
    w3t[c * 128 + k] = f2bf(w3[k * 256 + c] * s); }
  if (id < 8192) { int c = id >> 6, k = id & 63;
    float s = bng2[c] * rsqrtf(bnv2[c] + 1e-5f);
    w2t[c * 64 + k] = f2bf(w2[k * 128 + c] * s); }
  if (id < 4096) { int c = id >> 8, k = id & 255;
    wct[c * 256 + k] = f2bf(wc[k * 16 + c]); }     // wc transposed [16][256]
  if (id < 576) { int k = id / 64, c = id % 64;
    float s = bng1[c] * rsqrtf(bnv1[c] + 1e-5f);
    w1e[k * 64 + c] = w1[k * 64 + c] * s; }
  if (id < 64)  { float s = bng1[id] * rsqrtf(bnv1[id] + 1e-5f); be1[id] = (b1[id] - bnm1[id]) * s + bnb1[id]; }
  if (id < 128) { float s = bng2[id] * rsqrtf(bnv2[id] + 1e-5f); be2[id] = (b2[id] - bnm2[id]) * s + bnb2[id]; }
  if (id < 256) { float s = bng3[id] * rsqrtf(bnv3[id] + 1e-5f); be3[id] = (b3[id] - bnm3[id]) * s + bnb3[id]; }
  if (id < 9)   { float s = bng0[id] * rsqrtf(bnv0[id] + 1e-5f); s0[id] = s; t0[id] = bnb0[id] - bnm0[id] * s; }
}

// ---------------- per-point: voxel index (exact fp32), bitmap, cat_pt_ind out ----
__global__ void vox_kernel(
    const float* __restrict__ xyz, const int* __restrict__ bidx,
    unsigned* __restrict__ flatkeys, unsigned long long* __restrict__ bitmap,
    float* __restrict__ out_cat)
{
  const int j = blockIdx.x * 256 + threadIdx.x;
  if (j >= N_PTS) return;
  const float PI_F = 3.14159265358979323846f;       // == float32(np.pi)
  const float minb[3] = {0.0f, -PI_F, -4.0f};
  const float maxb[3] = {50.0f, PI_F, 2.0f};
  const float gm1[3]  = {479.0f, 359.0f, 31.0f};
  int ind[3];
  #pragma unroll
  for (int d = 0; d < 3; ++d) {
    float itv = (maxb[d] - minb[d]) / gm1[d];       // IEEE fp32 div (no fast-math)
    float x  = xyz[(size_t)j * 3 + d];
    float cl = fminf(fmaxf(x, minb[d]), maxb[d]);
    ind[d] = (int)floorf((cl - minb[d]) / itv);
  }
  const int bi = bidx[j];
  const unsigned flat = ((unsigned)(bi * 480 + ind[0]) * 360u + (unsigned)ind[1]) * 32u + (unsigned)ind[2];
  flatkeys[j] = flat;
  atomicOr(&bitmap[flat >> 6], 1ull << (flat & 63u));
  float* oc = out_cat + (size_t)j * 4;
  oc[0] = (float)bi; oc[1] = (float)ind[0]; oc[2] = (float)ind[1]; oc[3] = (float)ind[2];
}

// ---------------- bitmap popcount scan -> sorted unique ids + per-word prefix ----
__global__ void reduce_words(const unsigned long long* __restrict__ bm, unsigned* __restrict__ bsums) {
  __shared__ unsigned sh[256];
  const int w = blockIdx.x * 256 + threadIdx.x;     // exact coverage
  sh[threadIdx.x] = (unsigned)__popcll(bm[w]);
  __syncthreads();
  for (int s = 128; s > 0; s >>= 1) { if (threadIdx.x < s) sh[threadIdx.x] += sh[threadIdx.x + s]; __syncthreads(); }
  if (threadIdx.x == 0) bsums[blockIdx.x] = sh[0];
}

__global__ void scan_small(unsigned* __restrict__ d, int n) {   // one block, n <= 1024, in-place exclusive
  __shared__ unsigned sh[1024];
  const int t = threadIdx.x;
  unsigned own = (t < n) ? d[t] : 0u;
  sh[t] = own; __syncthreads();
  for (int off = 1; off < 1024; off <<= 1) {
    unsigned v = (t >= off) ? sh[t - off] : 0u;
    __syncthreads(); sh[t] += v; __syncthreads();
  }
  if (t < n) d[t] = sh[t] - own;
}

__global__ void scatter_unq(const unsigned long long* __restrict__ bm, const unsigned* __restrict__ bsums,
                            unsigned* __restrict__ wordpref, unsigned* __restrict__ unqvals,
                            float* __restrict__ out_unq) {
  __shared__ unsigned sh[256];
  const int t = threadIdx.x;
  const int w = blockIdx.x * 256 + t;
  unsigned long long word = bm[w];
  unsigned own = (unsigned)__popcll(word);
  sh[t] = own; __syncthreads();
  for (int off = 1; off < 256; off <<= 1) {
    unsigned v = (t >= off) ? sh[t - off] : 0u;
    __syncthreads(); sh[t] += v; __syncthreads();
  }
  unsigned r = bsums[blockIdx.x] + sh[t] - own;     // global exclusive prefix
  wordpref[w] = r;
  while (word) {
    int b = __builtin_ctzll(word);
    unsigned id = (unsigned)w * 64u + (unsigned)b;
    unqvals[r] = id;
    out_unq[r] = (float)id;                         // exact: id < 2^24
    ++r;
    word &= word - 1;
  }
}

// ---------------- inverse indices + segment sizes + packed label histogram ----
__global__ void inv_kernel(const unsigned* __restrict__ flatkeys, const unsigned long long* __restrict__ bm,
                           const unsigned* __restrict__ wordpref, const int* __restrict__ ptlab,
                           unsigned* __restrict__ unq_inv, unsigned* __restrict__ cnt, unsigned* __restrict__ counts) {
  const int j = blockIdx.x * 256 + threadIdx.x;
  if (j >= N_PTS) return;
  const unsigned f = flatkeys[j];
  const unsigned w = f >> 6, b = f & 63u;
  const unsigned r = wordpref[w] + (unsigned)__popcll(bm[w] & ((1ull << b) - 1ull));
  unq_inv[j] = r;
  atomicAdd(&cnt[r], 1u);
  const unsigned lab = (unsigned)ptlab[j];
  atomicAdd(&counts[(size_t)r * 10 + (lab >> 1)], 1u << ((lab & 1u) * 16));  // 2x16-bit packed
}

// ---------------- CSR build over segments ----
__global__ void reduce_cnt(const unsigned* __restrict__ cnt, unsigned* __restrict__ bsums) {
  __shared__ unsigned sh[256];
  const int j = blockIdx.x * 256 + threadIdx.x;
  sh[threadIdx.x] = (j < N_PTS) ? cnt[j] : 0u;
  __syncthreads();
  for (int s = 128; s > 0; s >>= 1) { if (threadIdx.x < s) sh[threadIdx.x] += sh[threadIdx.x + s]; __syncthreads(); }
  if (threadIdx.x == 0) bsums[blockIdx.x] = sh[0];
}
__global__ void scan_cnt(const unsigned* __restrict__ cnt, const unsigned* __restrict__ bsums,
                         unsigned* __restrict__ off, unsigned* __restrict__ cur) {
  __shared__ unsigned sh[256];
  const int t = threadIdx.x;
  const int j = blockIdx.x * 256 + t;
  unsigned own = (j < N_PTS) ? cnt[j] : 0u;
  sh[t] = own; __syncthreads();
  for (int o = 1; o < 256; o <<= 1) {
    unsigned v = (t >= o) ? sh[t - o] : 0u;
    __syncthreads(); sh[t] += v; __syncthreads();
  }
  if (j < N_PTS) { unsigned e = bsums[blockIdx.x] + sh[t] - own; off[j] = e; cur[j] = e; }
}
__global__ void plist_kernel(const unsigned* __restrict__ unq_inv, unsigned* __restrict__ cur,
                             unsigned* __restrict__ plist) {
  const int j = blockIdx.x * 256 + threadIdx.x;
  if (j >= N_PTS) return;
  plist[atomicAdd(&cur[unq_inv[j]], 1u)] = (unsigned)j;
}

// ---------------- per-voxel label argmax (first max wins), scatter into labels output ----
__global__ void labels_kernel(const unsigned* __restrict__ cnt, const unsigned* __restrict__ counts,
                              const unsigned* __restrict__ unqvals, float* __restrict__ out_lab) {
  const int u = blockIdx.x * 256 + threadIdx.x;
  if (u >= N_PTS) return;
  if (cnt[u] == 0) return;
  const unsigned* c = counts + (size_t)u * 10;
  int best = 0; unsigned bv = c[0] & 0xFFFFu;
  #pragma unroll
  for (int l = 1; l < 20; ++l) {
    unsigned v = (c[l >> 1] >> ((l & 1) * 16)) & 0xFFFFu;
    if (v > bv) { bv = v; best = l; }
  }
  out_lab[unqvals[u]] = (float)best;
}

__global__ void fill_unq_kernel(float* __restrict__ out_unq) {
  const int j = blockIdx.x * 256 + threadIdx.x;
  if (j < N_PTS) out_unq[j] = -1.0f;                // jnp.unique fill_value
}

// ---------------- empty segments: pooled = relu(bc) ----
__global__ void fillempty_kernel(const unsigned* __restrict__ cnt, const float* __restrict__ bc,
                                 float* __restrict__ out_pooled) {
  const int u = blockIdx.x * 256 + threadIdx.x;
  if (u >= N_PTS || cnt[u] != 0) return;
  #pragma unroll
  for (int c = 0; c < 16; ++c) out_pooled[(size_t)u * 16 + c] = fmaxf(bc[c], 0.f);
}

// ---------------- in-block GEMM stage: actOut[64,C] = act(actIn[64,K] @ Wt^T + bias) ----
template<int K, int C, int PIN, int POUT, bool RELU>
__device__ __forceinline__ void gemm_stage(
    const unsigned short* __restrict__ Wt,     // [C][K] bf16, global
    const float* __restrict__ bias,            // [C]
    const unsigned short* actIn,               // LDS [64][PIN]
    unsigned short* actOut,                    // LDS [64][POUT]
    unsigned short* wsh,                       // LDS [C][40] staging
    int tid)
{
  constexpr int NT = C / 64;                   // 16-col tiles per wave
  const int wave = tid >> 6, lane = tid & 63;
  const int l15  = lane & 15, quad = lane >> 4;
  f32x4 acc[4][NT];
  #pragma unroll
  for (int mt = 0; mt < 4; ++mt)
    #pragma unroll
    for (int nt = 0; nt < NT; ++nt) acc[mt][nt] = (f32x4){0.f, 0.f, 0.f, 0.f};
  for (int kc = 0; kc < K; kc += 32) {
    for (int e = tid * 8; e < C * 32; e += 2048) {
      int c = e >> 5, col = e & 31;
      *(short8*)&wsh[c * 40 + col] = *(const short8*)(Wt + (size_t)c * K + kc + col);
    }
    __syncthreads();
    bf16x8 b[NT];
    #pragma unroll
    for (int nt = 0; nt < NT; ++nt)
      b[nt] = __builtin_bit_cast(bf16x8, *(const short8*)&wsh[(wave * 16 * NT + nt * 16 + l15) * 40 + quad * 8]);
    #pragma unroll
    for (int mt = 0; mt < 4; ++mt) {
      bf16x8 a = __builtin_bit_cast(bf16x8, *(const short8*)&actIn[(mt * 16 + l15) * PIN + kc + quad * 8]);
      #pragma unroll
      for (int nt = 0; nt < NT; ++nt)
        acc[mt][nt] = __builtin_amdgcn_mfma_f32_16x16x32_bf16(a, b[nt], acc[mt][nt], 0, 0, 0);
    }
    __syncthreads();
  }
  #pragma unroll
  for (int mt = 0; mt < 4; ++mt)
    #pragma unroll
    for (int nt = 0; nt < NT; ++nt) {
      const int c0 = wave * 16 * NT + nt * 16 + l15;
      const float bs = bias[c0];
      #pragma unroll
      for (int r = 0; r < 4; ++r) {
        const int rl = mt * 16 + quad * 4 + r;   // C/D: col=lane&15, row=quad*4+reg
        float y = acc[mt][nt][r] + bs;
        if (RELU) y = fmaxf(y, 0.f);
        actOut[rl * POUT + c0] = f2bf(y);
      }
    }
  __syncthreads();
}

// ---------------- fused MLP + segment-max + compression, plist-ordered rows ----
// LDS pool (shorts): bufA [0,16896) | bufB [16896,25600) | wsh [25600,35840)
// bufC (stage-3 output, 64x264) aliases [16896, 33792) = bufB+wsh (both dead by then)
#define PA 264
#define PB 136

__global__ __launch_bounds__(256, 2) void mlp_pool_kernel(
    const float* __restrict__ ptfea, const float* __restrict__ xyz, const int* __restrict__ shuf,
    const unsigned* __restrict__ plist, const unsigned* __restrict__ unq_inv,
    const unsigned* __restrict__ offv, const unsigned* __restrict__ cnt,
    const float* __restrict__ s0, const float* __restrict__ t0,
    const float* __restrict__ w1e, const float* __restrict__ be1,
    const unsigned short* __restrict__ w2t, const float* __restrict__ be2,
    const unsigned short* __restrict__ w3t, const float* __restrict__ be3,
    const unsigned short* __restrict__ w4t, const float* __restrict__ b4,
    const unsigned short* __restrict__ wct, const float* __restrict__ bc,
    unsigned short* __restrict__ partials, float* __restrict__ out_pooled)
{
  __shared__ __align__(16) unsigned short pool[35840];
  __shared__ int segs[64];
  __shared__ int jrows[64];
  __shared__ int s_alast;
  __shared__ unsigned char s_lead[64], s_comp[64];
  unsigned short* bufA = pool;
  unsigned short* bufB = pool + 16896;
  unsigned short* wsh  = pool + 25600;
  unsigned short* bufC = pool + 16896;
  const int tid  = threadIdx.x;
  const int row0 = blockIdx.x * 64;

  if (tid == 0) s_alast = 0;
  if (tid < 64) {
    int j = (int)plist[row0 + tid];
    jrows[tid] = j;
    segs[tid] = (int)unq_inv[j];
  }
  __syncthreads();

  // ---- stage 0: features + bn0 + layer1 (scalar fp32), 4 threads/row x 16 cols ----
  {
    const int r = tid >> 2, part = tid & 3;
    const int sj = shuf[jrows[r]];
    const float PI_F = 3.14159265358979323846f;
    const float minb[3] = {0.0f, -PI_F, -4.0f};
    const float maxb[3] = {50.0f, PI_F, 2.0f};
    const float gm1[3]  = {479.0f, 359.0f, 31.0f};
    float x0[9];
    #pragma unroll
    for (int d = 0; d < 3; ++d) {
      float itv = (maxb[d] - minb[d]) / gm1[d];
      float x   = xyz[(size_t)sj * 3 + d];
      float cl  = fminf(fmaxf(x, minb[d]), maxb[d]);
      float fi  = floorf((cl - minb[d]) / itv);
      float center = (fi + 0.5f) * itv + minb[d];
      x0[d] = (x - center) * s0[d] + t0[d];           // bn0 folded
    }
    #pragma unroll
    for (int d = 0; d < 6; ++d) x0[3 + d] = ptfea[(size_t)sj * 6 + d] * s0[3 + d] + t0[3 + d];
    #pragma unroll
    for (int ci = 0; ci < 16; ++ci) {
      const int c = part * 16 + ci;
      float acc = be1[c];
      #pragma unroll
      for (int k = 0; k < 9; ++k) acc += x0[k] * w1e[k * 64 + c];
      bufA[r * PA + c] = f2bf(fmaxf(acc, 0.0f));
    }
  }
  __syncthreads();

  // ---- L2: [K=64 -> C=128], bufA -> bufB;  L3: [128 -> 256], bufB -> bufA;
  //      L4: [256 -> 256], bufA -> bufC (aliases bufB+wsh; both dead at epilogue) ----
  gemm_stage< 64, 128, PA, PB, true >(w2t, be2, bufA, bufB, wsh, tid);
  gemm_stage<128, 256, PB, PA, true >(w3t, be3, bufB, bufA, wsh, tid);
  gemm_stage<256, 256, PA, PA, false>(w4t, b4,  bufA, bufC, wsh, tid);

  // ---- run analysis: leaders, completeness, last-run leader ----
  if (tid < 64) {
    const int r = tid;
    bool lead = (r == 0) || (segs[r] != segs[r - 1]);
    s_lead[r] = lead ? 1 : 0;
    unsigned char comp = 0;
    if (lead) {
      atomicMax(&s_alast, r);
      int e = r + 1;
      while (e < 64 && segs[e] == segs[r]) ++e;
      const unsigned s = (unsigned)segs[r];
      comp = (offv[s] == (unsigned)(row0 + r) && offv[s] + cnt[s] == (unsigned)(row0 + e)) ? 1 : 0;
    }
    s_comp[r] = comp;
  }
  __syncthreads();

  // ---- backward segmented max scan (thread t owns column t), in place in bufC ----
  {
    const int c = tid;
    float cur = bf2f(bufC[63 * PA + c]);
    for (int r = 62; r >= 0; --r) {
      float x = bf2f(bufC[r * PA + c]);
      cur = (segs[r] == segs[r + 1]) ? fmaxf(cur, x) : x;
      bufC[r * PA + c] = f2bf(cur);
    }
  }
  __syncthreads();

  // ---- boundary partials (first/last incomplete runs) ----
  {
    const int c = tid;
    const int alast = s_alast;
    const bool finc = !s_comp[0];
    const bool linc = !s_comp[alast];
    const size_t b2 = (size_t)blockIdx.x * 2;
    if (finc) partials[b2 * 256 + c]       = bufC[0 * PA + c];
    if (linc) partials[(b2 + 1) * 256 + c] = bufC[alast * PA + c];
  }

  // ---- compression GEMM: PM[64,256] @ wct^T -> 16 outs; write complete-run leaders ----
  for (int e = tid * 8; e < 16 * 256; e += 2048) {
    int cc = e >> 8, k = e & 255;
    *(short8*)&bufA[cc * PA + k] = *(const short8*)(wct + cc * 256 + k);
  }
  __syncthreads();
  {
    const int wave = tid >> 6, lane = tid & 63;
    const int l15 = lane & 15, quad = lane >> 4;
    f32x4 acc = (f32x4){0.f, 0.f, 0.f, 0.f};
    #pragma unroll
    for (int kc = 0; kc < 256; kc += 32) {
      bf16x8 a = __builtin_bit_cast(bf16x8, *(const short8*)&bufC[(wave * 16 + l15) * PA + kc + quad * 8]);
      bf16x8 b = __builtin_bit_cast(bf16x8, *(const short8*)&bufA[l15 * PA + kc + quad * 8]);
      acc = __builtin_amdgcn_mfma_f32_16x16x32_bf16(a, b, acc, 0, 0, 0);
    }
    const float bcv = bc[l15];
    #pragma unroll
    for (int r = 0; r < 4; ++r) {
      const int rl = wave * 16 + quad * 4 + r;
      if (s_lead[rl] && s_comp[rl])
        out_pooled[(size_t)segs[rl] * 16 + l15] = fmaxf(acc[r] + bcv, 0.f);
    }
  }
}

// ---------------- merge block-spanning segments from partials ----
__global__ __launch_bounds__(256) void merge_kernel(
    const unsigned* __restrict__ plist, const unsigned* __restrict__ unq_inv,
    const unsigned* __restrict__ offv, const unsigned* __restrict__ cnt,
    const unsigned short* __restrict__ partials,
    const float* __restrict__ wc, const float* __restrict__ bc,
    float* __restrict__ out_pooled)
{
  __shared__ float pooled[256];
  __shared__ float psum[256];
  const int b = blockIdx.x;
  const unsigned s = unq_inv[plist[(size_t)b * 64 + 63]];
  const unsigned o = offv[s], e = o + cnt[s];
  if ((o >> 6) != (unsigned)b) return;              // owner = block where segment starts
  if (e <= (unsigned)(b + 1) * 64) return;          // doesn't span a boundary
  const int B1 = (int)((e - 1) >> 6);
  const int c = threadIdx.x;
  float m = bf2f(partials[((size_t)2 * b + 1) * 256 + c]);    // head partial (last run of b)
  for (int bb = b + 1; bb <= B1; ++bb)
    m = fmaxf(m, bf2f(partials[(size_t)2 * bb * 256 + c]));   // tails (first run of bb)
  pooled[c] = m;
  __syncthreads();
  const int co = c & 15, kg = c >> 4;
  float p = 0.f;
  #pragma unroll
  for (int k = kg * 16; k < kg * 16 + 16; ++k) p += pooled[k] * wc[k * 16 + co];
  psum[c] = p;
  __syncthreads();
  if (c < 16) {
    float acc = bc[c];
    #pragma unroll
    for (int g = 0; g < 16; ++g) acc += psum[g * 16 + c];
    out_pooled[(size_t)s * 16 + c] = fmaxf(acc, 0.f);
  }
}

extern "C" void kernel_launch(void* const* d_in, const int* in_sizes, int n_in,
                              void* d_out, int out_size, void* d_ws, size_t ws_size,
                              hipStream_t stream)
{
  const float* pt_fea = (const float*)d_in[0];
  const float* xyz    = (const float*)d_in[1];
  const int*   bidx   = (const int*)d_in[2];
  const int*   ptlab  = (const int*)d_in[3];
  const int*   shuf   = (const int*)d_in[4];
  const float* bng0 = (const float*)d_in[5],  *bnb0 = (const float*)d_in[6],  *bnm0 = (const float*)d_in[7],  *bnv0 = (const float*)d_in[8];
  const float* bng1 = (const float*)d_in[9],  *bnb1 = (const float*)d_in[10], *bnm1 = (const float*)d_in[11], *bnv1 = (const float*)d_in[12];
  const float* bng2 = (const float*)d_in[13], *bnb2 = (const float*)d_in[14], *bnm2 = (const float*)d_in[15], *bnv2 = (const float*)d_in[16];
  const float* bng3 = (const float*)d_in[17], *bnb3 = (const float*)d_in[18], *bnm3 = (const float*)d_in[19], *bnv3 = (const float*)d_in[20];
  const float* w1 = (const float*)d_in[21], *b1 = (const float*)d_in[22];
  const float* w2 = (const float*)d_in[23], *b2 = (const float*)d_in[24];
  const float* w3 = (const float*)d_in[25], *b3 = (const float*)d_in[26];
  const float* w4 = (const float*)d_in[27], *b4 = (const float*)d_in[28];
  const float* wc = (const float*)d_in[29], *bc = (const float*)d_in[30];

  float* out        = (float*)d_out;                // reference outputs are int64/f32/int32 -> float32 buffer
  float* out_unq    = out;                          // [240000]
  float* out_pooled = out + 240000;                 // [240000,16]
  float* out_lab    = out + 4080000;                // [2,480,360,32]
  float* out_cat    = out + 15139200;               // [240000,4]

  char* wsb = (char*)d_ws;
  size_t o = 0;
  auto alloc = [&](size_t bytes) -> void* { void* p = wsb + o; o = (o + bytes + 255) & ~(size_t)255; return p; };
  float* s0  = (float*)alloc(9 * 4);
  float* t0  = (float*)alloc(9 * 4);
  float* w1e = (float*)alloc(576 * 4);
  float* be1 = (float*)alloc(64 * 4);
  float* be2 = (float*)alloc(128 * 4);
  float* be3 = (float*)alloc(256 * 4);
  unsigned short* w2t = (unsigned short*)alloc(8192 * 2);
  unsigned short* w3t = (unsigned short*)alloc(32768 * 2);
  unsigned short* w4t = (unsigned short*)alloc(65536 * 2);
  unsigned short* wct = (unsigned short*)alloc(4096 * 2);
  unsigned* flatkeys = (unsigned*)alloc((size_t)N_PTS * 4);
  unsigned* unq_inv  = (unsigned*)alloc((size_t)N_PTS * 4);
  unsigned* unqvals  = (unsigned*)alloc((size_t)N_PTS * 4);
  unsigned* cnt      = (unsigned*)alloc((size_t)N_PTS * 4);
  unsigned* offv     = (unsigned*)alloc((size_t)N_PTS * 4);
  unsigned* cur      = (unsigned*)alloc((size_t)N_PTS * 4);
  unsigned* plist    = (unsigned*)alloc((size_t)N_PTS * 4);
  unsigned long long* bitmap = (unsigned long long*)alloc((size_t)NWORDS * 8);
  unsigned* wordpref = (unsigned*)alloc((size_t)NWORDS * 4);
  unsigned* bsumA    = (unsigned*)alloc(NB_WORD * 4);
  unsigned* bsumB    = (unsigned*)alloc(NB_PT * 4);
  unsigned* counts   = (unsigned*)alloc((size_t)N_PTS * 10 * 4);       // 2x16-bit packed
  unsigned short* partials = (unsigned short*)alloc((size_t)NBLK_MLP * 2 * 256 * 2);
  // total ~22.8 MB

  hipMemsetAsync(bitmap, 0, (size_t)NWORDS * 8, stream);
  hipMemsetAsync(cnt, 0, (size_t)N_PTS * 4, stream);
  hipMemsetAsync(counts, 0, (size_t)N_PTS * 10 * 4, stream);
  hipMemsetAsync(out_lab, 0, (size_t)NV * 4, stream);       // float 0.0f == all-zero bytes

  prep_kernel<<<256, 256, 0, stream>>>(bng0, bnb0, bnm0, bnv0, bng1, bnb1, bnm1, bnv1,
                                       bng2, bnb2, bnm2, bnv2, bng3, bnb3, bnm3, bnv3,
                                       w1, b1, w2, b2, w3, b3, w4, wc,
                                       s0, t0, w1e, be1, be2, be3, w2t, w3t, w4t, wct);
  fill_unq_kernel<<<NB_PT, 256, 0, stream>>>(out_unq);
  vox_kernel<<<NB_PT, 256, 0, stream>>>(xyz, bidx, flatkeys, bitmap, out_cat);
  reduce_words<<<NB_WORD, 256, 0, stream>>>(bitmap, bsumA);
  scan_small<<<1, 1024, 0, stream>>>(bsumA, NB_WORD);
  scatter_unq<<<NB_WORD, 256, 0, stream>>>(bitmap, bsumA, wordpref, unqvals, out_unq);
  inv_kernel<<<NB_PT, 256, 0, stream>>>(flatkeys, bitmap, wordpref, ptlab, unq_inv, cnt, counts);
  reduce_cnt<<<NB_PT, 256, 0, stream>>>(cnt, bsumB);
  scan_small<<<1, 1024, 0, stream>>>(bsumB, NB_PT);
  scan_cnt<<<NB_PT, 256, 0, stream>>>(cnt, bsumB, offv, cur);
  plist_kernel<<<NB_PT, 256, 0, stream>>>(unq_inv, cur, plist);
  labels_kernel<<<NB_PT, 256, 0, stream>>>(cnt, counts, unqvals, out_lab);
  fillempty_kernel<<<NB_PT, 256, 0, stream>>>(cnt, bc, out_pooled);
  mlp_pool_kernel<<<NBLK_MLP, 256, 0, stream>>>(pt_fea, xyz, shuf, plist, unq_inv, offv, cnt,
                                                s0, t0, w1e, be1, w2t, be2, w3t, be3, w4t, b4,
                                                wct, bc, partials, out_pooled);
  merge_kernel<<<NBLK_MLP, 256, 0, stream>>>(plist, unq_inv, offv, cnt, partials, wc, bc, out_pooled);
}

// Round 5
// 397.190 us; speedup vs baseline: 1.0936x; 1.0936x over previous
//
#include <hip/hip_runtime.h>
#include <stdint.h>

#define N_PTS 240000
#define NV    11059200      // 2*480*360*32 voxels
#define NWORDS 172800       // NV/64 bitmap words
#define NB_PT 938           // ceil(N_PTS/256)
#define NB_WORD 675         // NWORDS/256 (exact)
#define NBLK_MLP 3750       // N_PTS/64

typedef __bf16 bf16x8 __attribute__((ext_vector_type(8)));
typedef short  short8 __attribute__((ext_vector_type(8)));
typedef float  f32x4  __attribute__((ext_vector_type(4)));

__device__ __forceinline__ unsigned short f2bf(float f) {
  unsigned u = __builtin_bit_cast(unsigned, f);
  return (unsigned short)((u + 0x7FFFu + ((u >> 16) & 1u)) >> 16);   // RNE
}
__device__ __forceinline__ float bf2f(unsigned short h) {
  unsigned u = ((unsigned)h) << 16;
  return __builtin_bit_cast(float, u);
}

// ---------------- weight prep: fold BN into linear weights, transpose to [C][K] bf16 ----
__global__ void prep_kernel(
    const float* __restrict__ bng0, const float* __restrict__ bnb0, const float* __restrict__ bnm0, const float* __restrict__ bnv0,
    const float* __restrict__ bng1, const float* __restrict__ bnb1, const float* __restrict__ bnm1, const float* __restrict__ bnv1,
    const float* __restrict__ bng2, const float* __restrict__ bnb2, const float* __restrict__ bnm2, const float* __restrict__ bnv2,
    const float* __restrict__ bng3, const float* __restrict__ bnb3, const float* __restrict__ bnm3, const float* __restrict__ bnv3,
    const float* __restrict__ w1, const float* __restrict__ b1,
    const float* __restrict__ w2, const float* __restrict__ b2,
    const float* __restrict__ w3, const float* __restrict__ b3,
    const float* __restrict__ w4, const float* __restrict__ wc,
    float* __restrict__ s0, float* __restrict__ t0, float* __restrict__ w1e, float* __restrict__ be1,
    float* __restrict__ be2, float* __restrict__ be3,
    unsigned short* __restrict__ w2t, unsigned short* __restrict__ w3t, unsigned short* __restrict__ w4t,
    unsigned short* __restrict__ wct)
{
  const int id = blockIdx.x * 256 + threadIdx.x;   // grid covers 65536 exactly
  { int c = id >> 8, k = id & 255; w4t[c * 256 + k] = f2bf(w4[k * 256 + c]); }
  if (id < 32768) { int c = id >> 7, k = id & 127;
    float s = bng3[c] * rsqrtf(bnv3[c] + 1e-5f);
    w3t[c * 128 + k] = f2bf(w3[k * 256 + c] * s); }
  if (id < 8192) { int c = id >> 6, k = id & 63;
    float s = bng2[c] * rsqrtf(bnv2[c] + 1e-5f);
    w2t[c * 64 + k] = f2bf(w2[k * 128 + c] * s); }
  if (id < 4096) { int c = id >> 8, k = id & 255;
    wct[c * 256 + k] = f2bf(wc[k * 16 + c]); }     // wc transposed [16][256]
  if (id < 576) { int k = id / 64, c = id % 64;
    float s = bng1[c] * rsqrtf(bnv1[c] + 1e-5f);
    w1e[k * 64 + c] = w1[k * 64 + c] * s; }
  if (id < 64)  { float s = bng1[id] * rsqrtf(bnv1[id] + 1e-5f); be1[id] = (b1[id] - bnm1[id]) * s + bnb1[id]; }
  if (id < 128) { float s = bng2[id] * rsqrtf(bnv2[id] + 1e-5f); be2[id] = (b2[id] - bnm2[id]) * s + bnb2[id]; }
  if (id < 256) { float s = bng3[id] * rsqrtf(bnv3[id] + 1e-5f); be3[id] = (b3[id] - bnm3[id]) * s + bnb3[id]; }
  if (id < 9)   { float s = bng0[id] * rsqrtf(bnv0[id] + 1e-5f); s0[id] = s; t0[id] = bnb0[id] - bnm0[id] * s; }
}

// ---------------- per-point: voxel index (exact fp32), bitmap, cat_pt_ind out ----
__global__ void vox_kernel(
    const float* __restrict__ xyz, const int* __restrict__ bidx,
    unsigned* __restrict__ flatkeys, unsigned long long* __restrict__ bitmap,
    float* __restrict__ out_cat)
{
  const int j = blockIdx.x * 256 + threadIdx.x;
  if (j >= N_PTS) return;
  const float PI_F = 3.14159265358979323846f;       // == float32(np.pi)
  const float minb[3] = {0.0f, -PI_F, -4.0f};
  const float maxb[3] = {50.0f, PI_F, 2.0f};
  const float gm1[3]  = {479.0f, 359.0f, 31.0f};
  int ind[3];
  #pragma unroll
  for (int d = 0; d < 3; ++d) {
    float itv = (maxb[d] - minb[d]) / gm1[d];       // IEEE fp32 div (no fast-math)
    float x  = xyz[(size_t)j * 3 + d];
    float cl = fminf(fmaxf(x, minb[d]), maxb[d]);
    ind[d] = (int)floorf((cl - minb[d]) / itv);
  }
  const int bi = bidx[j];
  const unsigned flat = ((unsigned)(bi * 480 + ind[0]) * 360u + (unsigned)ind[1]) * 32u + (unsigned)ind[2];
  flatkeys[j] = flat;
  atomicOr(&bitmap[flat >> 6], 1ull << (flat & 63u));
  float* oc = out_cat + (size_t)j * 4;
  oc[0] = (float)bi; oc[1] = (float)ind[0]; oc[2] = (float)ind[1]; oc[3] = (float)ind[2];
}

// ---------------- bitmap popcount scan -> sorted unique ids + per-word prefix ----
__global__ void reduce_words(const unsigned long long* __restrict__ bm, unsigned* __restrict__ bsums) {
  __shared__ unsigned sh[256];
  const int w = blockIdx.x * 256 + threadIdx.x;     // exact coverage
  sh[threadIdx.x] = (unsigned)__popcll(bm[w]);
  __syncthreads();
  for (int s = 128; s > 0; s >>= 1) { if (threadIdx.x < s) sh[threadIdx.x] += sh[threadIdx.x + s]; __syncthreads(); }
  if (threadIdx.x == 0) bsums[blockIdx.x] = sh[0];
}

__global__ void scan_small(unsigned* __restrict__ d, int n) {   // one block, n <= 1024, in-place exclusive
  __shared__ unsigned sh[1024];
  const int t = threadIdx.x;
  unsigned own = (t < n) ? d[t] : 0u;
  sh[t] = own; __syncthreads();
  for (int off = 1; off < 1024; off <<= 1) {
    unsigned v = (t >= off) ? sh[t - off] : 0u;
    __syncthreads(); sh[t] += v; __syncthreads();
  }
  if (t < n) d[t] = sh[t] - own;
}

__global__ void scatter_unq(const unsigned long long* __restrict__ bm, const unsigned* __restrict__ bsums,
                            unsigned* __restrict__ wordpref, unsigned* __restrict__ unqvals,
                            float* __restrict__ out_unq) {
  __shared__ unsigned sh[256];
  const int t = threadIdx.x;
  const int w = blockIdx.x * 256 + t;
  unsigned long long word = bm[w];
  unsigned own = (unsigned)__popcll(word);
  sh[t] = own; __syncthreads();
  for (int off = 1; off < 256; off <<= 1) {
    unsigned v = (t >= off) ? sh[t - off] : 0u;
    __syncthreads(); sh[t] += v; __syncthreads();
  }
  unsigned r = bsums[blockIdx.x] + sh[t] - own;     // global exclusive prefix
  wordpref[w] = r;
  while (word) {
    int b = __builtin_ctzll(word);
    unsigned id = (unsigned)w * 64u + (unsigned)b;
    unqvals[r] = id;
    out_unq[r] = (float)id;                         // exact: id < 2^24
    ++r;
    word &= word - 1;
  }
}

// ---------------- inverse indices + segment sizes + packed label histogram ----
__global__ void inv_kernel(const unsigned* __restrict__ flatkeys, const unsigned long long* __restrict__ bm,
                           const unsigned* __restrict__ wordpref, const int* __restrict__ ptlab,
                           unsigned* __restrict__ unq_inv, unsigned* __restrict__ cnt, unsigned* __restrict__ counts) {
  const int j = blockIdx.x * 256 + threadIdx.x;
  if (j >= N_PTS) return;
  const unsigned f = flatkeys[j];
  const unsigned w = f >> 6, b = f & 63u;
  const unsigned r = wordpref[w] + (unsigned)__popcll(bm[w] & ((1ull << b) - 1ull));
  unq_inv[j] = r;
  atomicAdd(&cnt[r], 1u);
  const unsigned lab = (unsigned)ptlab[j];
  atomicAdd(&counts[(size_t)r * 10 + (lab >> 1)], 1u << ((lab & 1u) * 16));  // 2x16-bit packed
}

// ---------------- CSR build over segments ----
__global__ void reduce_cnt(const unsigned* __restrict__ cnt, unsigned* __restrict__ bsums) {
  __shared__ unsigned sh[256];
  const int j = blockIdx.x * 256 + threadIdx.x;
  sh[threadIdx.x] = (j < N_PTS) ? cnt[j] : 0u;
  __syncthreads();
  for (int s = 128; s > 0; s >>= 1) { if (threadIdx.x < s) sh[threadIdx.x] += sh[threadIdx.x + s]; __syncthreads(); }
  if (threadIdx.x == 0) bsums[blockIdx.x] = sh[0];
}
__global__ void scan_cnt(const unsigned* __restrict__ cnt, const unsigned* __restrict__ bsums,
                         unsigned* __restrict__ off, unsigned* __restrict__ cur) {
  __shared__ unsigned sh[256];
  const int t = threadIdx.x;
  const int j = blockIdx.x * 256 + t;
  unsigned own = (j < N_PTS) ? cnt[j] : 0u;
  sh[t] = own; __syncthreads();
  for (int o = 1; o < 256; o <<= 1) {
    unsigned v = (t >= o) ? sh[t - o] : 0u;
    __syncthreads(); sh[t] += v; __syncthreads();
  }
  if (j < N_PTS) { unsigned e = bsums[blockIdx.x] + sh[t] - own; off[j] = e; cur[j] = e; }
}
__global__ void plist_kernel(const unsigned* __restrict__ unq_inv, unsigned* __restrict__ cur,
                             unsigned* __restrict__ plist) {
  const int j = blockIdx.x * 256 + threadIdx.x;
  if (j >= N_PTS) return;
  plist[atomicAdd(&cur[unq_inv[j]], 1u)] = (unsigned)j;
}

// ---------------- per-voxel label argmax + empty-segment pooled fill ----
__global__ void labels_kernel(const unsigned* __restrict__ cnt, const unsigned* __restrict__ counts,
                              const unsigned* __restrict__ unqvals, const float* __restrict__ bc,
                              float* __restrict__ out_lab, float* __restrict__ out_pooled) {
  const int u = blockIdx.x * 256 + threadIdx.x;
  if (u >= N_PTS) return;
  if (cnt[u] == 0) {
    #pragma unroll
    for (int c = 0; c < 16; ++c) out_pooled[(size_t)u * 16 + c] = fmaxf(bc[c], 0.f);
    return;
  }
  const unsigned* c = counts + (size_t)u * 10;
  int best = 0; unsigned bv = c[0] & 0xFFFFu;
  #pragma unroll
  for (int l = 1; l < 20; ++l) {
    unsigned v = (c[l >> 1] >> ((l & 1) * 16)) & 0xFFFFu;
    if (v > bv) { bv = v; best = l; }
  }
  out_lab[unqvals[u]] = (float)best;
}

__global__ void fill_unq_kernel(float* __restrict__ out_unq) {
  const int j = blockIdx.x * 256 + threadIdx.x;
  if (j < N_PTS) out_unq[j] = -1.0f;                // jnp.unique fill_value
}

// ---- in-block GEMM stage: actOut[64,C] = act(actIn[64,K] @ Wt^T + bias) ----
// B fragments read DIRECTLY from global (weights are L1/L2-hot: shared by all blocks).
// No intra-k-loop barriers. In-place (actOut == actIn) is safe: barrier before epilogue.
template<int K, int C, int PIN, int POUT, bool RELU>
__device__ __forceinline__ void gemm_stage(
    const unsigned short* __restrict__ Wt,     // [C][K] bf16, global
    const float* __restrict__ bias,            // [C]
    const unsigned short* actIn,               // LDS [64][PIN]
    unsigned short* actOut,                    // LDS [64][POUT] (may alias actIn)
    int tid)
{
  constexpr int NT = C / 64;                   // 16-col tiles per wave
  const int wave = tid >> 6, lane = tid & 63;
  const int l15  = lane & 15, quad = lane >> 4;
  f32x4 acc[4][NT];
  #pragma unroll
  for (int mt = 0; mt < 4; ++mt)
    #pragma unroll
    for (int nt = 0; nt < NT; ++nt) acc[mt][nt] = (f32x4){0.f, 0.f, 0.f, 0.f};
  const unsigned short* wp[NT];
  #pragma unroll
  for (int nt = 0; nt < NT; ++nt)
    wp[nt] = Wt + (size_t)(wave * 16 * NT + nt * 16 + l15) * K + quad * 8;
  #pragma unroll
  for (int kc = 0; kc < K; kc += 32) {
    bf16x8 b[NT];
    #pragma unroll
    for (int nt = 0; nt < NT; ++nt)
      b[nt] = __builtin_bit_cast(bf16x8, *(const short8*)(wp[nt] + kc));
    #pragma unroll
    for (int mt = 0; mt < 4; ++mt) {
      bf16x8 a = __builtin_bit_cast(bf16x8, *(const short8*)&actIn[(mt * 16 + l15) * PIN + kc + quad * 8]);
      #pragma unroll
      for (int nt = 0; nt < NT; ++nt)
        acc[mt][nt] = __builtin_amdgcn_mfma_f32_16x16x32_bf16(a, b[nt], acc[mt][nt], 0, 0, 0);
    }
  }
  __syncthreads();                             // all k-loop LDS reads done (enables in-place)
  #pragma unroll
  for (int mt = 0; mt < 4; ++mt)
    #pragma unroll
    for (int nt = 0; nt < NT; ++nt) {
      const int c0 = wave * 16 * NT + nt * 16 + l15;
      const float bs = bias[c0];
      #pragma unroll
      for (int r = 0; r < 4; ++r) {
        const int rl = mt * 16 + quad * 4 + r;   // C/D: col=lane&15, row=quad*4+reg
        float y = acc[mt][nt][r] + bs;
        if (RELU) y = fmaxf(y, 0.f);
        actOut[rl * POUT + c0] = f2bf(y);
      }
    }
  __syncthreads();
}

// ---------------- fused MLP + segment-max + compression, plist-ordered rows ----
// LDS: bufA 64x264 (33792 B) + bufB 64x136 (17408 B) ~= 51.5 KB -> 3 blocks/CU
#define PA 264
#define PB 136

__global__ __launch_bounds__(256, 3) void mlp_pool_kernel(
    const float* __restrict__ ptfea, const float* __restrict__ xyz, const int* __restrict__ shuf,
    const unsigned* __restrict__ plist, const unsigned* __restrict__ unq_inv,
    const unsigned* __restrict__ offv, const unsigned* __restrict__ cnt,
    const float* __restrict__ s0, const float* __restrict__ t0,
    const float* __restrict__ w1e, const float* __restrict__ be1,
    const unsigned short* __restrict__ w2t, const float* __restrict__ be2,
    const unsigned short* __restrict__ w3t, const float* __restrict__ be3,
    const unsigned short* __restrict__ w4t, const float* __restrict__ b4,
    const unsigned short* __restrict__ wct, const float* __restrict__ bc,
    unsigned short* __restrict__ partials, float* __restrict__ out_pooled)
{
  __shared__ __align__(16) unsigned short bufA[64 * PA];
  __shared__ __align__(16) unsigned short bufB[64 * PB];
  __shared__ int segs[64];
  __shared__ int jrows[64];
  __shared__ int s_alast;
  __shared__ unsigned char s_lead[64], s_comp[64];
  const int tid  = threadIdx.x;
  const int row0 = blockIdx.x * 64;

  if (tid == 0) s_alast = 0;
  if (tid < 64) {
    int j = (int)plist[row0 + tid];
    jrows[tid] = j;
    segs[tid] = (int)unq_inv[j];
  }
  __syncthreads();

  // ---- stage 0: features + bn0 + layer1 (scalar fp32), 4 threads/row x 16 cols ----
  {
    const int r = tid >> 2, part = tid & 3;
    const int sj = shuf[jrows[r]];
    const float PI_F = 3.14159265358979323846f;
    const float minb[3] = {0.0f, -PI_F, -4.0f};
    const float maxb[3] = {50.0f, PI_F, 2.0f};
    const float gm1[3]  = {479.0f, 359.0f, 31.0f};
    float x0[9];
    #pragma unroll
    for (int d = 0; d < 3; ++d) {
      float itv = (maxb[d] - minb[d]) / gm1[d];
      float x   = xyz[(size_t)sj * 3 + d];
      float cl  = fminf(fmaxf(x, minb[d]), maxb[d]);
      float fi  = floorf((cl - minb[d]) / itv);
      float center = (fi + 0.5f) * itv + minb[d];
      x0[d] = (x - center) * s0[d] + t0[d];           // bn0 folded
    }
    #pragma unroll
    for (int d = 0; d < 6; ++d) x0[3 + d] = ptfea[(size_t)sj * 6 + d] * s0[3 + d] + t0[3 + d];
    #pragma unroll
    for (int ci = 0; ci < 16; ++ci) {
      const int c = part * 16 + ci;
      float acc = be1[c];
      #pragma unroll
      for (int k = 0; k < 9; ++k) acc += x0[k] * w1e[k * 64 + c];
      bufA[r * PA + c] = f2bf(fmaxf(acc, 0.0f));
    }
  }
  __syncthreads();

  // ---- L2: [64->128] bufA->bufB;  L3: [128->256] bufB->bufA;  L4: [256->256] bufA in-place ----
  gemm_stage< 64, 128, PA, PB, true >(w2t, be2, bufA, bufB, tid);
  gemm_stage<128, 256, PB, PA, true >(w3t, be3, bufB, bufA, tid);
  gemm_stage<256, 256, PA, PA, false>(w4t, b4,  bufA, bufA, tid);

  // ---- run analysis: leaders, completeness, last-run leader ----
  if (tid < 64) {
    const int r = tid;
    bool lead = (r == 0) || (segs[r] != segs[r - 1]);
    s_lead[r] = lead ? 1 : 0;
    unsigned char comp = 0;
    if (lead) {
      atomicMax(&s_alast, r);
      int e = r + 1;
      while (e < 64 && segs[e] == segs[r]) ++e;
      const unsigned s = (unsigned)segs[r];
      comp = (offv[s] == (unsigned)(row0 + r) && offv[s] + cnt[s] == (unsigned)(row0 + e)) ? 1 : 0;
    }
    s_comp[r] = comp;
  }
  __syncthreads();

  // ---- backward segmented max scan (thread t owns column t), in place in bufA ----
  {
    const int c = tid;
    float cur = bf2f(bufA[63 * PA + c]);
    for (int r = 62; r >= 0; --r) {
      float x = bf2f(bufA[r * PA + c]);
      cur = (segs[r] == segs[r + 1]) ? fmaxf(cur, x) : x;
      bufA[r * PA + c] = f2bf(cur);
    }
  }
  __syncthreads();

  // ---- boundary partials (first/last incomplete runs) ----
  {
    const int c = tid;
    const int alast = s_alast;
    const size_t b2 = (size_t)blockIdx.x * 2;
    if (!s_comp[0])     partials[b2 * 256 + c]       = bufA[0 * PA + c];
    if (!s_comp[alast]) partials[(b2 + 1) * 256 + c] = bufA[alast * PA + c];
  }

  // ---- compression GEMM: PM[64,256] @ wct^T -> 16 outs; write complete-run leaders ----
  {
    const int wave = tid >> 6, lane = tid & 63;
    const int l15 = lane & 15, quad = lane >> 4;
    const unsigned short* wp = wct + l15 * 256 + quad * 8;
    f32x4 acc = (f32x4){0.f, 0.f, 0.f, 0.f};
    #pragma unroll
    for (int kc = 0; kc < 256; kc += 32) {
      bf16x8 a = __builtin_bit_cast(bf16x8, *(const short8*)&bufA[(wave * 16 + l15) * PA + kc + quad * 8]);
      bf16x8 b = __builtin_bit_cast(bf16x8, *(const short8*)(wp + kc));
      acc = __builtin_amdgcn_mfma_f32_16x16x32_bf16(a, b, acc, 0, 0, 0);
    }
    const float bcv = bc[l15];
    #pragma unroll
    for (int r = 0; r < 4; ++r) {
      const int rl = wave * 16 + quad * 4 + r;
      if (s_lead[rl] && s_comp[rl])
        out_pooled[(size_t)segs[rl] * 16 + l15] = fmaxf(acc[r] + bcv, 0.f);
    }
  }
}

// ---------------- merge block-spanning segments from partials ----
__global__ __launch_bounds__(256) void merge_kernel(
    const unsigned* __restrict__ plist, const unsigned* __restrict__ unq_inv,
    const unsigned* __restrict__ offv, const unsigned* __restrict__ cnt,
    const unsigned short* __restrict__ partials,
    const float* __restrict__ wc, const float* __restrict__ bc,
    float* __restrict__ out_pooled)
{
  __shared__ float pooled[256];
  __shared__ float psum[256];
  const int b = blockIdx.x;
  const unsigned s = unq_inv[plist[(size_t)b * 64 + 63]];
  const unsigned o = offv[s], e = o + cnt[s];
  if ((o >> 6) != (unsigned)b) return;              // owner = block where segment starts
  if (e <= (unsigned)(b + 1) * 64) return;          // doesn't span a boundary
  const int B1 = (int)((e - 1) >> 6);
  const int c = threadIdx.x;
  float m = bf2f(partials[((size_t)2 * b + 1) * 256 + c]);    // head partial (last run of b)
  for (int bb = b + 1; bb <= B1; ++bb)
    m = fmaxf(m, bf2f(partials[(size_t)2 * bb * 256 + c]));   // tails (first run of bb)
  pooled[c] = m;
  __syncthreads();
  const int co = c & 15, kg = c >> 4;
  float p = 0.f;
  #pragma unroll
  for (int k = kg * 16; k < kg * 16 + 16; ++k) p += pooled[k] * wc[k * 16 + co];
  psum[c] = p;
  __syncthreads();
  if (c < 16) {
    float acc = bc[c];
    #pragma unroll
    for (int g = 0; g < 16; ++g) acc += psum[g * 16 + c];
    out_pooled[(size_t)s * 16 + c] = fmaxf(acc, 0.f);
  }
}

extern "C" void kernel_launch(void* const* d_in, const int* in_sizes, int n_in,
                              void* d_out, int out_size, void* d_ws, size_t ws_size,
                              hipStream_t stream)
{
  const float* pt_fea = (const float*)d_in[0];
  const float* xyz    = (const float*)d_in[1];
  const int*   bidx   = (const int*)d_in[2];
  const int*   ptlab  = (const int*)d_in[3];
  const int*   shuf   = (const int*)d_in[4];
  const float* bng0 = (const float*)d_in[5],  *bnb0 = (const float*)d_in[6],  *bnm0 = (const float*)d_in[7],  *bnv0 = (const float*)d_in[8];
  const float* bng1 = (const float*)d_in[9],  *bnb1 = (const float*)d_in[10], *bnm1 = (const float*)d_in[11], *bnv1 = (const float*)d_in[12];
  const float* bng2 = (const float*)d_in[13], *bnb2 = (const float*)d_in[14], *bnm2 = (const float*)d_in[15], *bnv2 = (const float*)d_in[16];
  const float* bng3 = (const float*)d_in[17], *bnb3 = (const float*)d_in[18], *bnm3 = (const float*)d_in[19], *bnv3 = (const float*)d_in[20];
  const float* w1 = (const float*)d_in[21], *b1 = (const float*)d_in[22];
  const float* w2 = (const float*)d_in[23], *b2 = (const float*)d_in[24];
  const float* w3 = (const float*)d_in[25], *b3 = (const float*)d_in[26];
  const float* w4 = (const float*)d_in[27], *b4 = (const float*)d_in[28];
  const float* wc = (const float*)d_in[29], *bc = (const float*)d_in[30];

  float* out        = (float*)d_out;                // reference outputs are int64/f32/int32 -> float32 buffer
  float* out_unq    = out;                          // [240000]
  float* out_pooled = out + 240000;                 // [240000,16]
  float* out_lab    = out + 4080000;                // [2,480,360,32]
  float* out_cat    = out + 15139200;               // [240000,4]

  char* wsb = (char*)d_ws;
  size_t o = 0;
  auto alloc = [&](size_t bytes) -> void* { void* p = wsb + o; o = (o + bytes + 255) & ~(size_t)255; return p; };
  float* s0  = (float*)alloc(9 * 4);
  float* t0  = (float*)alloc(9 * 4);
  float* w1e = (float*)alloc(576 * 4);
  float* be1 = (float*)alloc(64 * 4);
  float* be2 = (float*)alloc(128 * 4);
  float* be3 = (float*)alloc(256 * 4);
  unsigned short* w2t = (unsigned short*)alloc(8192 * 2);
  unsigned short* w3t = (unsigned short*)alloc(32768 * 2);
  unsigned short* w4t = (unsigned short*)alloc(65536 * 2);
  unsigned short* wct = (unsigned short*)alloc(4096 * 2);
  unsigned* flatkeys = (unsigned*)alloc((size_t)N_PTS * 4);
  unsigned* unq_inv  = (unsigned*)alloc((size_t)N_PTS * 4);
  unsigned* unqvals  = (unsigned*)alloc((size_t)N_PTS * 4);
  unsigned* cnt      = (unsigned*)alloc((size_t)N_PTS * 4);
  unsigned* offv     = (unsigned*)alloc((size_t)N_PTS * 4);
  unsigned* cur      = (unsigned*)alloc((size_t)N_PTS * 4);
  unsigned* plist    = (unsigned*)alloc((size_t)N_PTS * 4);
  unsigned long long* bitmap = (unsigned long long*)alloc((size_t)NWORDS * 8);
  unsigned* wordpref = (unsigned*)alloc((size_t)NWORDS * 4);
  unsigned* bsumA    = (unsigned*)alloc(NB_WORD * 4);
  unsigned* bsumB    = (unsigned*)alloc(NB_PT * 4);
  unsigned* counts   = (unsigned*)alloc((size_t)N_PTS * 10 * 4);       // 2x16-bit packed
  unsigned short* partials = (unsigned short*)alloc((size_t)NBLK_MLP * 2 * 256 * 2);
  // total ~22.8 MB

  hipMemsetAsync(bitmap, 0, (size_t)NWORDS * 8, stream);
  hipMemsetAsync(cnt, 0, (size_t)N_PTS * 4, stream);
  hipMemsetAsync(counts, 0, (size_t)N_PTS * 10 * 4, stream);
  hipMemsetAsync(out_lab, 0, (size_t)NV * 4, stream);       // float 0.0f == all-zero bytes

  prep_kernel<<<256, 256, 0, stream>>>(bng0, bnb0, bnm0, bnv0, bng1, bnb1, bnm1, bnv1,
                                       bng2, bnb2, bnm2, bnv2, bng3, bnb3, bnm3, bnv3,
                                       w1, b1, w2, b2, w3, b3, w4, wc,
                                       s0, t0, w1e, be1, be2, be3, w2t, w3t, w4t, wct);
  fill_unq_kernel<<<NB_PT, 256, 0, stream>>>(out_unq);
  vox_kernel<<<NB_PT, 256, 0, stream>>>(xyz, bidx, flatkeys, bitmap, out_cat);
  reduce_words<<<NB_WORD, 256, 0, stream>>>(bitmap, bsumA);
  scan_small<<<1, 1024, 0, stream>>>(bsumA, NB_WORD);
  scatter_unq<<<NB_WORD, 256, 0, stream>>>(bitmap, bsumA, wordpref, unqvals, out_unq);
  inv_kernel<<<NB_PT, 256, 0, stream>>>(flatkeys, bitmap, wordpref, ptlab, unq_inv, cnt, counts);
  reduce_cnt<<<NB_PT, 256, 0, stream>>>(cnt, bsumB);
  scan_small<<<1, 1024, 0, stream>>>(bsumB, NB_PT);
  scan_cnt<<<NB_PT, 256, 0, stream>>>(cnt, bsumB, offv, cur);
  plist_kernel<<<NB_PT, 256, 0, stream>>>(unq_inv, cur, plist);
  labels_kernel<<<NB_PT, 256, 0, stream>>>(cnt, counts, unqvals, bc, out_lab, out_pooled);
  mlp_pool_kernel<<<NBLK_MLP, 256, 0, stream>>>(pt_fea, xyz, shuf, plist, unq_inv, offv, cnt,
                                                s0, t0, w1e, be1, w2t, be2, w3t, be3, w4t, b4,
                                                wct, bc, partials, out_pooled);
  merge_kernel<<<NBLK_MLP, 256, 0, stream>>>(plist, unq_inv, offv, cnt, partials, wc, bc, out_pooled);
}